// Round 4
// baseline (6698.543 us; speedup 1.0000x reference)
//
#include <hip/hip_runtime.h>
#include <cstdint>

#define TT 128   // time steps (= bucket_size)
#define BB 128   // batch
#define II 512   // input dim
#define HH 512   // hidden dim
#define DD 1024  // I + H
#define NC 513   // H + 1
#define NPAD 520 // row pitch for lnXW / vbuf (bf16)
#define NT 36    // n-tiles of 16 in big GEMM (576 padded cols)
#define NT2 33   // n-tiles of 16 in recurrence GEMM packing
#define XST 520  // xch row pitch (floats)
#define G8 8    // row groups (16 rows each)
#define EPSL 1e-5f

typedef short    s8v  __attribute__((ext_vector_type(8)));
typedef _Float16 h8v  __attribute__((ext_vector_type(8)));
typedef float    f4v  __attribute__((ext_vector_type(4)));
typedef ushort   u16x8 __attribute__((ext_vector_type(8)));
typedef ushort   u16x4 __attribute__((ext_vector_type(4)));

__device__ __forceinline__ ushort f2bf(float f){
  uint u = __builtin_bit_cast(uint, f);
  uint r = (u + 0x7fffu + ((u >> 16) & 1u)) >> 16;
  return (ushort)r;
}
__device__ __forceinline__ float bf2f(ushort s){
  uint u = ((uint)s) << 16;
  return __builtin_bit_cast(float, u);
}
__device__ __forceinline__ float hsig(float x){
  return fminf(fmaxf(0.2f * x + 0.5f, 0.f), 1.f);
}
// fast tanh: (e^{2x}-1)/(e^{2x}+1) via exp2; |err| ~1e-6
__device__ __forceinline__ float ftanh(float x){
  float ax = fminf(fabsf(x), 15.f);
  float e  = __builtin_amdgcn_exp2f(ax * 2.885390082f);   // 2*log2(e)
  float r  = (e - 1.f) * __builtin_amdgcn_rcpf(e + 1.f);
  return __builtin_copysignf(r, x);
}

// ---------------- pre-pack W / U into MFMA B-fragment order (bf16, big GEMM) ----
__global__ void prepack_B(const float* __restrict__ src, ushort* __restrict__ dst){
  int idx = blockIdx.x * 256 + threadIdx.x;
  if (idx >= 128 * NT * 16 * 8) return;
  int kl = idx & 7;
  int ni = (idx >> 3) & 15;
  int nt = (idx >> 7) % NT;
  int kc = idx / (NT * 16 * 8);
  int k = kc * 8 + kl;
  int n = nt * 16 + ni;
  float v = (n < NC) ? src[k * NC + n] : 0.f;
  dst[idx] = f2bf(v);
}

// ---------------- pre-pack U_hi (rows I..I+511) in f16 B-fragment order ---------
__global__ void prepack_Uhi_f16(const float* __restrict__ U, ushort* __restrict__ dst){
  int idx = blockIdx.x * 256 + threadIdx.x;
  if (idx >= 64 * NT2 * 16 * 8) return;
  int kl = idx & 7;
  int ni = (idx >> 3) & 15;
  int nt = (idx >> 7) % NT2;
  int kc = idx / (NT2 * 16 * 8);
  int k = II + kc * 8 + kl;
  int n = nt * 16 + ni;
  float v = (n < NC) ? U[(size_t)k * NC + n] : 0.f;
  _Float16 h = (_Float16)v;
  dst[idx] = __builtin_bit_cast(ushort, h);
}

// ---------------- fused GEMM (+ optional row-LayerNorm) -------------------
__global__ __launch_bounds__(1024) void gemm_ln(
    const float* __restrict__ A, int amode, int ksteps,
    const ushort* __restrict__ Bpk, ushort* __restrict__ out,
    int do_ln, const float* __restrict__ gam, const float* __restrict__ bet,
    const float* __restrict__ bias)
{
  __shared__ ushort As[64][40];
  __shared__ float red[4][4][16][2];
  int tid = threadIdx.x;
  int lane = tid & 63, wid = tid >> 6;
  int quad = lane >> 4, l16 = lane & 15;
  int wm = wid >> 2, wn = wid & 3;
  int blk = blockIdx.x;

  f4v acc[9];
#pragma unroll
  for (int i = 0; i < 9; i++) acc[i] = (f4v){0.f, 0.f, 0.f, 0.f};

  int arow = tid >> 4;
  int acp  = tid & 15;
  int r = blk * 64 + arow;
  const float* aptr;
  if (amode == 0){ int t = r >> 7, b = r & 127; aptr = A + ((size_t)(b * TT + t)) * II + acp * 2; }
  else           { aptr = A + (size_t)r * DD + acp * 2; }

  for (int ks = 0; ks < ksteps; ks++){
    __syncthreads();
    float2 a2 = *(const float2*)(aptr + ks * 32);
    uint pk = (uint)f2bf(a2.x) | ((uint)f2bf(a2.y) << 16);
    *(uint*)&As[arow][acp * 2] = pk;
    __syncthreads();
    s8v af = *(const s8v*)&As[wm * 16 + l16][quad * 8];
    int kc = ks * 4 + quad;
    const s8v* bp = (const s8v*)Bpk + (size_t)kc * (NT * 16) + l16;
#pragma unroll
    for (int i = 0; i < 9; i++){
      s8v bf = bp[(wn * 9 + i) * 16];
      acc[i] = __builtin_amdgcn_mfma_f32_16x16x32_bf16(af, bf, acc[i], 0, 0, 0);
    }
  }

  int rowbase = blk * 64 + wm * 16 + quad * 4;
  if (do_ln){
    float s1[4], s2[4];
#pragma unroll
    for (int g = 0; g < 4; g++){
      float a = 0.f, q = 0.f;
#pragma unroll
      for (int i = 0; i < 9; i++){ float v = acc[i][g]; a += v; q += v * v; }
#pragma unroll
      for (int m = 1; m < 16; m <<= 1){ a += __shfl_xor(a, m, 64); q += __shfl_xor(q, m, 64); }
      s1[g] = a; s2[g] = q;
    }
    if (l16 == 0){
#pragma unroll
      for (int g = 0; g < 4; g++){
        red[wm][wn][quad * 4 + g][0] = s1[g];
        red[wm][wn][quad * 4 + g][1] = s2[g];
      }
    }
    __syncthreads();
#pragma unroll
    for (int g = 0; g < 4; g++){
      int rr = quad * 4 + g;
      float S1 = red[wm][0][rr][0] + red[wm][1][rr][0] + red[wm][2][rr][0] + red[wm][3][rr][0];
      float S2 = red[wm][0][rr][1] + red[wm][1][rr][1] + red[wm][2][rr][1] + red[wm][3][rr][1];
      float mean = S1 * (1.f / 513.f);
      float var  = S2 * (1.f / 513.f) - mean * mean;
      float inv  = 1.f / (sqrtf(var + EPSL) + EPSL);
      size_t rg = (size_t)(rowbase + g);
#pragma unroll
      for (int i = 0; i < 9; i++){
        int n = wn * 144 + i * 16 + l16;
        if (n < NC){
          float val = gam[n] * ((acc[i][g] - mean) * inv) + bet[n] + bias[n];
          out[rg * NPAD + n] = f2bf(val);
        }
      }
    }
  } else {
#pragma unroll
    for (int g = 0; g < 4; g++){
      size_t rg = (size_t)(rowbase + g);
#pragma unroll
      for (int i = 0; i < 9; i++){
        int n = wn * 144 + i * 16 + l16;
        if (n < NC) out[rg * NPAD + n] = f2bf(acc[i][g]);
      }
    }
  }
}

// ---------------- recurrence: 16 batch rows per chain, 4-way column split --------
// grid = 32 blocks (co-resident). bid: cc = bid>>3 (column slice of 128), g = bid&7
// (row group of 16 batch rows). 512 threads = 8 waves; wave w handles rows 2w,2w+1
// (half-wave each) for gather/stats/gates/tanh/update, and GEMM n-tile cc*8+w with
// its 16 K-fragments of U PINNED IN REGISTERS for the whole kernel.
// The per-step GEMV is a real 16-row MFMA GEMM: A rows = 16 batch rows' tanh.
// Exchange: slices of v via agent-scope relaxed atomics; one release-counter per
// row group (8 waves x 4 blocks = 32 increments/step).
__global__ __launch_bounds__(512) void rnn_layer(
    int layer,
    const float* __restrict__ x,
    float* __restrict__ h_seq,
    const ushort* __restrict__ lnXW,
    ushort* __restrict__ vbuf,
    const float* __restrict__ fkRd, const float* __restrict__ hvRd,
    float* __restrict__ fkWr, float* __restrict__ hvWr,
    const ushort* __restrict__ Upk2,
    const float* __restrict__ U,
    const int* __restrict__ mask,
    const float* __restrict__ gam1, const float* __restrict__ bet1,
    const float* __restrict__ bias,
    float* __restrict__ out,
    float* __restrict__ xch,
    int* __restrict__ flags)
{
  __shared__ __align__(16) ushort tanh16[16][512];   // f16 tanh, XOR-swizzled rows
  __shared__ __align__(16) float  tanhf32[16][512];  // f32 tanh, XOR-swizzled rows
  __shared__ __align__(16) float  ylds[8][16][16];   // per-tile y output

  int tid = threadIdx.x;            // 0..511
  int bid = blockIdx.x;             // 0..31
  int cc  = bid >> 3;               // column slice 0..3
  int g   = bid & 7;                // row group 0..7
  int lane = tid & 63, wid = tid >> 6;      // 8 waves
  int h    = lane >> 5, lane32 = lane & 31; // half-wave = one batch row
  int quad = (lane >> 4) & 3, l16 = lane & 15;
  int rw   = 2 * wid + h;           // local row 0..15
  int rwg  = g * 16 + rw;           // global batch row
  int k0   = lane32 * 16;           // this lane's K window [k0, k0+16)
  int nbase = cc * 128;
  int ncol  = nbase + lane32 * 4;   // own 4 v/h columns
  const bool lastL = (layer == 3);
  int* cnt = flags + g;

  // ---- persistent registers ----
  int gt = cc * 8 + wid;            // this wave's global n-tile
  h8v ufr[16];
  {
    const h8v* Ub = (const h8v*)Upk2;
#pragma unroll
    for (int ks = 0; ks < 16; ks++)
      ufr[ks] = Ub[((size_t)(ks * 4 + quad) * NT2 + gt) * 16 + l16];
  }
  float g1r[16], b1r[16];
#pragma unroll
  for (int j = 0; j < 16; j++){ g1r[j] = gam1[k0 + j + 1]; b1r[j] = bet1[k0 + j + 1]; }
  float ucr[16];
#pragma unroll
  for (int j = 0; j < 16; j++) ucr[j] = U[(size_t)(II + k0 + j) * NC + 512];
  float g10 = gam1[0], b10 = bet1[0], bias0 = bias[0];

  // per-thread state
  f4v sv   = (f4v){0.f,0.f,0.f,0.f};     // own v columns
  f4v h_lo = (f4v){0.f,0.f,0.f,0.f};
  f4v h_hi = (f4v){0.f,0.f,0.f,0.f};
  float v5 = 0.f;                         // col 512 (cc==3, lane32==0)
  float fkc = 0.f, hvc = 0.f;             // gate carries (uniform per half-wave)
  int sw = (rw & 7) << 4;

  for (int t = 0; t < TT; t++){
    // pin persistent regs (defeat reload-per-iteration)
#pragma unroll
    for (int i = 0; i < 16; i++) asm volatile("" : "+v"(ufr[i]));
#pragma unroll
    for (int i = 0; i < 16; i++) asm volatile("" : "+v"(g1r[i]), "+v"(b1r[i]));

    size_t row = (size_t)(t * BB + rwg);

    // ---- early plain loads (independent of partner state) ----
    u16x8 W0 = *(const u16x8*)&lnXW[row * NPAD + k0];
    u16x8 W1 = *(const u16x8*)&lnXW[row * NPAD + k0 + 8];
    ushort w16 = lnXW[row * NPAD + k0 + 16];
    float lw0 = bf2f(lnXW[row * NPAD]);
    u16x4 xu4 = *(const u16x4*)&vbuf[row * NPAD + ncol];
    f4v xlo4, xhi4;
    if (layer == 0){
      xlo4 = *(const f4v*)&x[((size_t)(rwg * TT + t)) * II + ncol];
      xhi4 = (f4v){0.f,0.f,0.f,0.f};
    } else {
      xlo4 = *(const f4v*)&h_seq[row * DD + ncol];
      xhi4 = *(const f4v*)&h_seq[row * DD + 512 + ncol];
    }
    float fkp_tm1 = 0.f, fkp = 0.f, hvp = 1.f;
    if (layer > 0){
      fkp_tm1 = fkRd[t * BB + rwg];
      fkp = (t + 1 < TT) ? fkRd[(t + 1) * BB + rwg] : 0.f;
      hvp = hvRd[t * BB + rwg];
    }
    float xu5 = (cc == 3 && lane32 == 0) ? bf2f(vbuf[row * NPAD + 512]) : 0.f;
    int mraw  = mask[rwg * TT + t];
    int mprev = (t > 0) ? mask[rwg * TT + t - 1] : 0;

    // ---- poll + gather full v row (agent atomics, L1-bypassing) ----
    float va[17];
    if (t > 0){
      int target = 32 * (layer * TT + t);
      if (lane == 0){
        while (__hip_atomic_load(cnt, __ATOMIC_RELAXED, __HIP_MEMORY_SCOPE_AGENT) < target)
          __builtin_amdgcn_s_sleep(1);
      }
      __builtin_amdgcn_sched_barrier(0);
      const float* xr = xch + ((size_t)((t & 1) * G8 + g) * 16 + rw) * XST;
#pragma unroll
      for (int j = 0; j < 17; j++)
        va[j] = __hip_atomic_load(xr + k0 + j, __ATOMIC_RELAXED, __HIP_MEMORY_SCOPE_AGENT);
    } else {
#pragma unroll
      for (int j = 0; j < 17; j++) va[j] = 0.f;
    }

    // ---- LN stats over 513 cols (32-lane reduce per row) ----
    float a = (lane32 == 0) ? va[0] : 0.f;
    float q = a * a;
#pragma unroll
    for (int j = 1; j <= 16; j++){ float v = va[j]; a += v; q += v * v; }
#pragma unroll
    for (int m = 1; m < 32; m <<= 1){ a += __shfl_xor(a, m, 64); q += __shfl_xor(q, m, 64); }
    float mean = a * (1.f / 513.f);
    float var  = q * (1.f / 513.f) - mean * mean;
    float inv  = 1.f / (sqrtf(var + EPSL) + EPSL);
    float v0   = __shfl(va[0], lane & 32, 64);

    // ---- gates (uniform per half-wave) ----
    bool mk  = mraw > 0;
    bool mk2 = (t > 0) && (mprev > 0) && !mk;
    float sum20 = (v0 - mean) * inv * g10 + b10;
    float s0 = lw0 + sum20;
    float fk_both = hsig(s0);
    float fk_t1   = hsig(sum20 + bias0);
    float fk = fkp_tm1 + (1.f - fkp_tm1) * (fkc * fk_both + (1.f - fkc) * fk_t1);
    if (mk2) fk = 0.f;
    float h_only = hvc * fk * (fkp + (1.f - fkp) * (1.f - hvp));
    float x_only = hvp * (1.f - fkp) * (1.f - fk + fk * (1.f - hvc));
    float both   = (1.f - fkp) * fk * hvc * hvp;
    float hv = 1.f - (1.f - h_only) * (1.f - x_only) * (1.f - both);
    fkc = mk ? fk : fkc;
    hvc = mk ? hv : hvc;
    if (mk2) fkc = 0.f;

    // ---- tanh for own 16 K-cols; stage to LDS (f16 swizzled + f32 swizzled) ----
    float th[16];
#pragma unroll
    for (int j = 0; j < 16; j++){
      ushort lwu = (j < 7) ? W0[j + 1] : ((j < 15) ? W1[j - 7] : w16);
      float s = bf2f(lwu) + (va[j + 1] - mean) * inv * g1r[j] + b1r[j];
      th[j] = ftanh(s);
    }
    {
      char* t16b = (char*)&tanh16[0][0] + rw * 1024;
      u16x8 p0, p1;
#pragma unroll
      for (int j = 0; j < 8; j++){
        p0[j] = __builtin_bit_cast(ushort, (_Float16)th[j]);
        p1[j] = __builtin_bit_cast(ushort, (_Float16)th[j + 8]);
      }
      *(u16x8*)(t16b + ((lane32 * 32 +  0) ^ sw)) = p0;
      *(u16x8*)(t16b + ((lane32 * 32 + 16) ^ sw)) = p1;
      char* t32b = (char*)&tanhf32[0][0] + rw * 2048;
#pragma unroll
      for (int q2 = 0; q2 < 4; q2++){
        f4v tv = (f4v){th[q2*4+0], th[q2*4+1], th[q2*4+2], th[q2*4+3]};
        *(f4v*)(t32b + ((lane32 * 64 + q2 * 16) ^ sw)) = tv;
      }
    }
    __syncthreads();   // B1: tanh staged

    // ---- GEMM: wave's n-tile, A = 16 batch rows, U from registers ----
    {
      f4v a0 = (f4v){0.f,0.f,0.f,0.f}, a1 = a0;
      char* tb = (char*)&tanh16[0][0] + l16 * 1024;
      int swr = (l16 & 7) << 4;
#pragma unroll
      for (int ks = 0; ks < 16; ks += 2){
        h8v af0 = *(const h8v*)(tb + (((ks    ) * 64 + quad * 16) ^ swr));
        h8v af1 = *(const h8v*)(tb + (((ks + 1) * 64 + quad * 16) ^ swr));
        a0 = __builtin_amdgcn_mfma_f32_16x16x32_f16(af0, ufr[ks    ], a0, 0, 0, 0);
        a1 = __builtin_amdgcn_mfma_f32_16x16x32_f16(af1, ufr[ks + 1], a1, 0, 0, 0);
      }
#pragma unroll
      for (int i = 0; i < 4; i++)
        ylds[wid][quad * 4 + i][l16] = a0[i] + a1[i];
    }
    // col-512 dot on VALU (cc==3): y512 per row via half-wave reduce
    float y512 = 0.f;
    if (cc == 3){
      float p = 0.f;
#pragma unroll
      for (int j = 0; j < 16; j++) p = fmaf(th[j], ucr[j], p);
#pragma unroll
      for (int m = 1; m < 32; m <<= 1) p += __shfl_xor(p, m, 64);
      y512 = p;
    }
    __syncthreads();   // B2: y ready

    // ---- state update + publish (critical path), then flag ----
    f4v y4 = *(const f4v*)((const char*)&ylds[0][0][0]
                           + (lane32 >> 2) * 1024 + rw * 64 + (lane32 & 3) * 16);
    f4v xuf = (f4v){bf2f(xu4[0]), bf2f(xu4[1]), bf2f(xu4[2]), bf2f(xu4[3])};
    if (mk) sv = h_only * sv + x_only * xuf + both * y4;
    {
      float* xw = xch + ((size_t)(((t + 1) & 1) * G8 + g) * 16 + rw) * XST;
#pragma unroll
      for (int i = 0; i < 4; i++)
        __hip_atomic_store(xw + ncol + i, sv[i], __ATOMIC_RELAXED, __HIP_MEMORY_SCOPE_AGENT);
      if (cc == 3 && lane32 == 0){
        float nv5 = h_only * v5 + x_only * xu5 + both * y512;
        if (mk) v5 = nv5;
        __hip_atomic_store(xw + 512, v5, __ATOMIC_RELAXED, __HIP_MEMORY_SCOPE_AGENT);
      }
    }
    if (lane == 0)
      __hip_atomic_fetch_add(cnt, 1, __ATOMIC_RELEASE, __HIP_MEMORY_SCOPE_AGENT);

    // ---- deferred work (off the inter-block critical path) ----
    f4v th4 = *(const f4v*)((const char*)&tanhf32[0][0]
                            + rw * 2048 + ((nbase * 4 + lane32 * 16) ^ sw));
    if (mk){
      h_lo = h_only * h_lo + x_only * xlo4;
      h_hi = h_only * h_hi + x_only * xhi4 + both * th4;
    }
    if (!lastL){
      u16x4 pv;
#pragma unroll
      for (int i = 0; i < 4; i++) pv[i] = f2bf(sv[i]);
      *(u16x4*)&vbuf[row * NPAD + ncol] = pv;
      *(f4v*)&h_seq[row * DD + ncol] = h_lo;
      *(f4v*)&h_seq[row * DD + 512 + ncol] = h_hi;
      if (cc == 3 && lane32 == 0) vbuf[row * NPAD + 512] = f2bf(v5);
      if (cc == 0 && lane32 == 0){ fkWr[t * BB + rwg] = fkc; hvWr[t * BB + rwg] = hvc; }
    }
    if (lastL && t == TT - 1) *(f4v*)&out[(size_t)rwg * HH + ncol] = h_hi;
  }
}

extern "C" void kernel_launch(void* const* d_in, const int* in_sizes, int n_in,
                              void* d_out, int out_size, void* d_ws, size_t ws_size,
                              hipStream_t stream)
{
  (void)in_sizes; (void)n_in; (void)out_size; (void)ws_size;
  const float* x      = (const float*)d_in[0];
  const int*   mask   = (const int*)d_in[1];
  const float* W      = (const float*)d_in[2];
  const float* U      = (const float*)d_in[3];
  const float* bias   = (const float*)d_in[4];
  const float* gammas = (const float*)d_in[5];
  const float* betas  = (const float*)d_in[6];
  float* out = (float*)d_out;

  char* ws = (char*)d_ws;
  size_t off = 0;
  auto alloc = [&](size_t bytes) -> void* {
    void* p = ws + off;
    off += (bytes + 255) & ~(size_t)255;
    return p;
  };
  float*  h_seq = (float*) alloc((size_t)TT * BB * DD * 4);
  ushort* lnXW  = (ushort*)alloc((size_t)TT * BB * NPAD * 2);
  ushort* vbuf  = (ushort*)alloc((size_t)TT * BB * NPAD * 2);
  float*  fkbuf = (float*) alloc((size_t)2 * TT * BB * 4);   // layer-parity double buffer
  float*  hvbuf = (float*) alloc((size_t)2 * TT * BB * 4);
  ushort* Wpk   = (ushort*)alloc((size_t)128 * NT * 16 * 8 * 2);
  ushort* Upk   = (ushort*)alloc((size_t)128 * NT * 16 * 8 * 2);
  ushort* Upk2  = (ushort*)alloc((size_t)64 * NT2 * 16 * 8 * 2);
  float*  xch   = (float*) alloc((size_t)2 * G8 * 16 * XST * 4);  // parity x group x row
  int*    flags = (int*)   alloc((size_t)G8 * 4);

  hipMemsetAsync(flags, 0, (size_t)G8 * 4, stream);

  int npk = 128 * NT * 16 * 8;
  prepack_B<<<dim3((npk + 255) / 256), dim3(256), 0, stream>>>(W, Wpk);
  prepack_B<<<dim3((npk + 255) / 256), dim3(256), 0, stream>>>(U, Upk);
  int npk2 = 64 * NT2 * 16 * 8;
  prepack_Uhi_f16<<<dim3((npk2 + 255) / 256), dim3(256), 0, stream>>>(U, Upk2);

  const float* g0 = gammas,      *g1 = gammas + NC;
  const float* be0 = betas,      *be1 = betas + NC;

  // layer 0: lnXW = LN(x @ W_lo)+b ; vbuf = x @ U_lo (raw)
  gemm_ln<<<dim3(256), dim3(1024), 0, stream>>>(x, 0, 16, Wpk, lnXW, 1, g0, be0, bias);
  gemm_ln<<<dim3(256), dim3(1024), 0, stream>>>(x, 0, 16, Upk, vbuf, 0, g0, be0, bias);

  for (int d = 0; d < 4; d++){
    if (d > 0)
      gemm_ln<<<dim3(256), dim3(1024), 0, stream>>>(h_seq, 1, 32, Wpk, lnXW, 1, g0, be0, bias);
    const float* fkRd = fkbuf + ((size_t)((d + 1) & 1)) * TT * BB;
    const float* hvRd = hvbuf + ((size_t)((d + 1) & 1)) * TT * BB;
    float* fkWr = fkbuf + ((size_t)(d & 1)) * TT * BB;
    float* hvWr = hvbuf + ((size_t)(d & 1)) * TT * BB;
    rnn_layer<<<dim3(32), dim3(512), 0, stream>>>(d, x, h_seq, lnXW, vbuf,
                                                  fkRd, hvRd, fkWr, hvWr,
                                                  Upk2, U, mask, g1, be1, bias, out,
                                                  xch, flags);
  }
}

// Round 5
// 3036.155 us; speedup vs baseline: 2.2063x; 2.2063x over previous
//
#include <hip/hip_runtime.h>
#include <cstdint>

#define TT 128   // time steps (= bucket_size)
#define BB 128   // batch
#define II 512   // input dim
#define HH 512   // hidden dim
#define DD 1024  // I + H
#define NC 513   // H + 1
#define NPAD 520 // row pitch for lnXW / vbuf (bf16)
#define NT 36    // n-tiles of 16 in big GEMM (576 padded cols)
#define EPSL 1e-5f

typedef short    s8v  __attribute__((ext_vector_type(8)));
typedef float    f4v  __attribute__((ext_vector_type(4)));
typedef _Float16 h2v  __attribute__((ext_vector_type(2)));

__device__ __forceinline__ ushort f2bf(float f){
  uint u = __builtin_bit_cast(uint, f);
  uint r = (u + 0x7fffu + ((u >> 16) & 1u)) >> 16;
  return (ushort)r;
}
__device__ __forceinline__ float bf2f(ushort s){
  uint u = ((uint)s) << 16;
  return __builtin_bit_cast(float, u);
}
__device__ __forceinline__ float hsig(float x){
  return fminf(fmaxf(0.2f * x + 0.5f, 0.f), 1.f);
}
// fast tanh via exp2; |err| ~1e-6
__device__ __forceinline__ float ftanh(float x){
  float ax = fminf(fabsf(x), 15.f);
  float e  = __builtin_amdgcn_exp2f(ax * 2.885390082f);   // 2*log2(e)
  float r  = (e - 1.f) * __builtin_amdgcn_rcpf(e + 1.f);
  return __builtin_copysignf(r, x);
}
// f32 += dot(f16x2, f16x2) — exact products, f32 accumulate
__device__ __forceinline__ float dot2(uint a, uint b, float c){
#if __has_builtin(__builtin_amdgcn_fdot2)
  return __builtin_amdgcn_fdot2(__builtin_bit_cast(h2v, a),
                                __builtin_bit_cast(h2v, b), c, false);
#else
  h2v x = __builtin_bit_cast(h2v, a), y = __builtin_bit_cast(h2v, b);
  return fmaf((float)x[1], (float)y[1], fmaf((float)x[0], (float)y[0], c));
#endif
}

// ---------------- pre-pack W / U into MFMA B-fragment order (bf16, big GEMM) ----
__global__ void prepack_B(const float* __restrict__ src, ushort* __restrict__ dst){
  int idx = blockIdx.x * 256 + threadIdx.x;
  if (idx >= 128 * NT * 16 * 8) return;
  int kl = idx & 7;
  int ni = (idx >> 3) & 15;
  int nt = (idx >> 7) % NT;
  int kc = idx / (NT * 16 * 8);
  int k = kc * 8 + kl;
  int n = nt * 16 + ni;
  float v = (n < NC) ? src[k * NC + n] : 0.f;
  dst[idx] = f2bf(v);
}

// ---------------- pre-pack U_hi (rows II..II+511) as f16 pairs for fdot2 --------
// uint idx = (c*512 + n)*4 + j holds f16 pair (U[II+8c+2j][n], U[II+8c+2j+1][n]).
// GEMV reads uint4 at (c*512 + n): pairs k = 8c..8c+7 for column n.
__global__ void prepack_Uhi_pk(const float* __restrict__ U, uint* __restrict__ dst,
                               float* __restrict__ ucol){
  int idx = blockIdx.x * 256 + threadIdx.x;
  if (idx < 64 * 512 * 4){
    int j = idx & 3;
    int n = (idx >> 2) & 511;
    int c = idx >> 11;
    int k0 = II + 8 * c + 2 * j;
    _Float16 lo = (_Float16)U[(size_t)k0 * NC + n];
    _Float16 hi = (_Float16)U[(size_t)(k0 + 1) * NC + n];
    dst[idx] = (uint)__builtin_bit_cast(ushort, lo)
             | ((uint)__builtin_bit_cast(ushort, hi) << 16);
  }
  if (idx < 512) ucol[idx] = U[(size_t)(II + idx) * NC + 512];
}

// ---------------- fused GEMM (+ optional row-LayerNorm) -------------------
__global__ __launch_bounds__(1024) void gemm_ln(
    const float* __restrict__ A, int amode, int ksteps,
    const ushort* __restrict__ Bpk, ushort* __restrict__ out,
    int do_ln, const float* __restrict__ gam, const float* __restrict__ bet,
    const float* __restrict__ bias)
{
  __shared__ ushort As[64][40];
  __shared__ float red[4][4][16][2];
  int tid = threadIdx.x;
  int lane = tid & 63, wid = tid >> 6;
  int quad = lane >> 4, l16 = lane & 15;
  int wm = wid >> 2, wn = wid & 3;
  int blk = blockIdx.x;

  f4v acc[9];
#pragma unroll
  for (int i = 0; i < 9; i++) acc[i] = (f4v){0.f, 0.f, 0.f, 0.f};

  int arow = tid >> 4;
  int acp  = tid & 15;
  int r = blk * 64 + arow;
  const float* aptr;
  if (amode == 0){ int t = r >> 7, b = r & 127; aptr = A + ((size_t)(b * TT + t)) * II + acp * 2; }
  else           { aptr = A + (size_t)r * DD + acp * 2; }

  for (int ks = 0; ks < ksteps; ks++){
    __syncthreads();
    float2 a2 = *(const float2*)(aptr + ks * 32);
    uint pk = (uint)f2bf(a2.x) | ((uint)f2bf(a2.y) << 16);
    *(uint*)&As[arow][acp * 2] = pk;
    __syncthreads();
    s8v af = *(const s8v*)&As[wm * 16 + l16][quad * 8];
    int kc = ks * 4 + quad;
    const s8v* bp = (const s8v*)Bpk + (size_t)kc * (NT * 16) + l16;
#pragma unroll
    for (int i = 0; i < 9; i++){
      s8v bf = bp[(wn * 9 + i) * 16];
      acc[i] = __builtin_amdgcn_mfma_f32_16x16x32_bf16(af, bf, acc[i], 0, 0, 0);
    }
  }

  int rowbase = blk * 64 + wm * 16 + quad * 4;
  if (do_ln){
    float s1[4], s2[4];
#pragma unroll
    for (int g = 0; g < 4; g++){
      float a = 0.f, q = 0.f;
#pragma unroll
      for (int i = 0; i < 9; i++){ float v = acc[i][g]; a += v; q += v * v; }
#pragma unroll
      for (int m = 1; m < 16; m <<= 1){ a += __shfl_xor(a, m, 64); q += __shfl_xor(q, m, 64); }
      s1[g] = a; s2[g] = q;
    }
    if (l16 == 0){
#pragma unroll
      for (int g = 0; g < 4; g++){
        red[wm][wn][quad * 4 + g][0] = s1[g];
        red[wm][wn][quad * 4 + g][1] = s2[g];
      }
    }
    __syncthreads();
#pragma unroll
    for (int g = 0; g < 4; g++){
      int rr = quad * 4 + g;
      float S1 = red[wm][0][rr][0] + red[wm][1][rr][0] + red[wm][2][rr][0] + red[wm][3][rr][0];
      float S2 = red[wm][0][rr][1] + red[wm][1][rr][1] + red[wm][2][rr][1] + red[wm][3][rr][1];
      float mean = S1 * (1.f / 513.f);
      float var  = S2 * (1.f / 513.f) - mean * mean;
      float inv  = 1.f / (sqrtf(var + EPSL) + EPSL);
      size_t rg = (size_t)(rowbase + g);
#pragma unroll
      for (int i = 0; i < 9; i++){
        int n = wn * 144 + i * 16 + l16;
        if (n < NC){
          float val = gam[n] * ((acc[i][g] - mean) * inv) + bet[n] + bias[n];
          out[rg * NPAD + n] = f2bf(val);
        }
      }
    }
  } else {
#pragma unroll
    for (int g = 0; g < 4; g++){
      size_t rg = (size_t)(rowbase + g);
#pragma unroll
      for (int i = 0; i < 9; i++){
        int n = wn * 144 + i * 16 + l16;
        if (n < NC) out[rg * NPAD + n] = f2bf(acc[i][g]);
      }
    }
  }
}

// ---------------- per-batch-row sequential recurrence (intra-block only) ----
// one block per batch row; 512 threads = 8 waves; thread n owns column n.
// 2 barriers per step. GEMV via v_dot2_f32_f16 (f16-pair packed U, f32 accum).
// Col-512 state v512 is a UNIFORM register on every thread, updated at step
// start from the previous step's red_p partials (no extra barrier, no serial
// thread-0 section). Gates computed redundantly (bitwise-identical) by all.
__global__ __launch_bounds__(512) void rnn_layer(
    int layer,
    const float* __restrict__ x,
    float* __restrict__ h_seq,
    const ushort* __restrict__ lnXW,
    ushort* __restrict__ vbuf,
    float* __restrict__ fkbuf,
    float* __restrict__ hvbuf,
    const uint* __restrict__ Upk4,
    const float* __restrict__ ucol,
    const int* __restrict__ mask,
    const float* __restrict__ gam1, const float* __restrict__ bet1,
    const float* __restrict__ bias,
    float* __restrict__ out)
{
  __shared__ __align__(16) ushort tanh16[512];  // f16 tanh (GEMV operand, pair-packed)
  __shared__ __align__(16) float  tanhvf[512];  // f32 tanh (h update / col-512 dot)
  __shared__ float red_a[8], red_q[8], red_p[8];
  __shared__ float sh_v0;
  __shared__ int msk[TT];

  int tid = threadIdx.x;
  int b = blockIdx.x;
  int lane = tid & 63, wid = tid >> 6;
  const bool lastL = (layer == 3);

  float sv = 0.f;                    // own v column
  float v512 = 0.f;                  // uniform on all threads
  float h_lo = 0.f, h_hi = 0.f;
  float fkc = 0.f, hvc = 0.f;        // uniform gate carries
  float g1n = gam1[tid], b1n = bet1[tid];
  float g10 = gam1[0],  b10 = bet1[0];
  float g1e = gam1[512], b1e = bet1[512];
  float bias0 = bias[0];
  float uc = ucol[tid];
  // previous-step gates for the deferred (uniform) col-512 update
  float ho_p = 0.f, xo_p = 0.f, bo_p = 0.f, xu5_p = 0.f;
  int mk_p = 0;

  if (tid < TT) msk[tid] = mask[b * TT + tid];
  if (lane == 0){ red_a[wid] = 0.f; red_q[wid] = 0.f; red_p[wid] = 0.f; }
  if (tid == 0) sh_v0 = 0.f;
  __syncthreads();

  for (int t = 0; t < TT; t++){
    size_t row = (size_t)(t * BB + b);

    // ---- P0: issue this step's loads
    float lw    = bf2f(lnXW[row * NPAD + tid]);
    float lw0   = bf2f(lnXW[row * NPAD]);
    float lw512 = bf2f(lnXW[row * NPAD + 512]);
    float xu    = bf2f(vbuf[row * NPAD + tid]);
    float xu5   = bf2f(vbuf[row * NPAD + 512]);      // broadcast (uniform)
    float xlo, xhi;
    if (layer == 0){ xlo = x[((size_t)(b * TT + t)) * II + tid]; xhi = 0.f; }
    else { xlo = h_seq[row * DD + tid]; xhi = h_seq[row * DD + 512 + tid]; }
    float fkp_tm1 = 0.f, fkp = 0.f, hvp = 1.f;
    if (layer > 0){
      fkp_tm1 = fkbuf[t * BB + b];
      fkp = (t + 1 < TT) ? fkbuf[(t + 1) * BB + b] : 0.f;
      hvp = hvbuf[t * BB + b];
    }
    int mraw  = msk[t];
    int mprev = (t > 0) ? msk[t - 1] : 0;

    // ---- P1: uniform col-512 update (prev step), LN stats, gates (all threads)
    if (t > 0){
      float y512 = red_p[0] + red_p[1] + red_p[2] + red_p[3]
                 + red_p[4] + red_p[5] + red_p[6] + red_p[7];
      float nv5 = ho_p * v512 + xo_p * xu5_p + bo_p * y512;
      if (mk_p) v512 = nv5;
      if (tid == 0 && !lastL) vbuf[(row - BB) * NPAD + 512] = f2bf(v512);
    }
    float S = red_a[0] + red_a[1] + red_a[2] + red_a[3]
            + red_a[4] + red_a[5] + red_a[6] + red_a[7];
    float Q = red_q[0] + red_q[1] + red_q[2] + red_q[3]
            + red_q[4] + red_q[5] + red_q[6] + red_q[7];
    S += v512; Q += v512 * v512;
    float v0 = sh_v0;
    float mean = S * (1.f / 513.f);
    float var  = Q * (1.f / 513.f) - mean * mean;
    float inv  = 1.f / (sqrtf(var + EPSL) + EPSL);

    bool mk  = mraw > 0;
    bool mk2 = (t > 0) && (mprev > 0) && !mk;
    float sum20 = (v0 - mean) * inv * g10 + b10;
    float s0 = lw0 + sum20;
    float fk_both = hsig(s0);
    float fk_t1   = hsig(sum20 + bias0);
    float fk = fkp_tm1 + (1.f - fkp_tm1) * (fkc * fk_both + (1.f - fkc) * fk_t1);
    if (mk2) fk = 0.f;
    float h_only = hvc * fk * (fkp + (1.f - fkp) * (1.f - hvp));
    float x_only = hvp * (1.f - fkp) * (1.f - fk + fk * (1.f - hvc));
    float both   = (1.f - fkp) * fk * hvc * hvp;
    float hv = 1.f - (1.f - h_only) * (1.f - x_only) * (1.f - both);
    fkc = mk ? fk : fkc;
    hvc = mk ? hv : hvc;
    if (mk2) fkc = 0.f;

    // ---- P2: LN apply + tanh; stage f16 (pair-packed via layout) and f32
    {
      float sum2 = (sv - mean) * inv * g1n + b1n;
      float s = lw + sum2;
      float th = ftanh(s);
      if (tid == 0){
        float sum2e = (v512 - mean) * inv * g1e + b1e;
        float the = ftanh(lw512 + sum2e);
        tanh16[511] = __builtin_bit_cast(ushort, (_Float16)the);
        tanhvf[511] = the;
      } else {
        tanh16[tid - 1] = __builtin_bit_cast(ushort, (_Float16)th);
        tanhvf[tid - 1] = th;
      }
    }
    __syncthreads();   // B1: tanh staged

    // ---- P3: GEMV y[n] = sum_k tanh[k] * U_hi[k][n] via fdot2
    float y0 = 0.f, y1 = 0.f, y2 = 0.f, y3 = 0.f;
    {
      const uint4* up = (const uint4*)Upk4 + tid;
      const uint4* tp = (const uint4*)tanh16;
#pragma unroll 16
      for (int c = 0; c < 64; c++){
        uint4 uu = up[(size_t)c * 512];   // coalesced 16B / lane
        uint4 tt = tp[c];                 // LDS broadcast
        y0 = dot2(tt.x, uu.x, y0);
        y1 = dot2(tt.y, uu.y, y1);
        y2 = dot2(tt.z, uu.z, y2);
        y3 = dot2(tt.w, uu.w, y3);
      }
    }
    float y = (y0 + y1) + (y2 + y3);
    // col-512 partial: this thread's tanh (core col tid) x U[II+tid][512]
    {
      float p = tanhvf[tid] * uc;
#pragma unroll
      for (int m = 1; m < 64; m <<= 1) p += __shfl_xor(p, m, 64);
      if (lane == 0) red_p[wid] = p;     // read next step (after step-start barrier)
    }

    // ---- P4: state updates, stream writes, next-step LN stats
    float nv = h_only * sv + x_only * xu + both * y;
    if (mk) sv = nv;
    float thh = tanhvf[tid];
    float nh_lo = h_only * h_lo + x_only * xlo;
    float nh_hi = h_only * h_hi + x_only * xhi + both * thh;
    if (mk){ h_lo = nh_lo; h_hi = nh_hi; }
    if (!lastL){
      vbuf[row * NPAD + tid] = f2bf(sv);
      h_seq[row * DD + tid] = h_lo;
      h_seq[row * DD + 512 + tid] = h_hi;
      if (tid == 0){ fkbuf[t * BB + b] = fkc; hvbuf[t * BB + b] = hvc; }
    }
    if (lastL && t == TT - 1) out[b * HH + tid] = h_hi;

    ho_p = h_only; xo_p = x_only; bo_p = both; mk_p = mk ? 1 : 0; xu5_p = xu5;

    {
      float a = sv, q = sv * sv;
#pragma unroll
      for (int m = 1; m < 64; m <<= 1){ a += __shfl_xor(a, m, 64); q += __shfl_xor(q, m, 64); }
      if (lane == 0){ red_a[wid] = a; red_q[wid] = q; }
      if (tid == 0) sh_v0 = sv;
    }
    __syncthreads();   // B2 (= next step's start barrier)
  }

  // epilogue: final col-512 update (t = TT-1)
  if (tid == 0 && !lastL){
    float y512 = red_p[0] + red_p[1] + red_p[2] + red_p[3]
               + red_p[4] + red_p[5] + red_p[6] + red_p[7];
    float nv5 = ho_p * v512 + xo_p * xu5_p + bo_p * y512;
    if (mk_p) v512 = nv5;
    vbuf[(size_t)((TT - 1) * BB + b) * NPAD + 512] = f2bf(v512);
  }
}

extern "C" void kernel_launch(void* const* d_in, const int* in_sizes, int n_in,
                              void* d_out, int out_size, void* d_ws, size_t ws_size,
                              hipStream_t stream)
{
  (void)in_sizes; (void)n_in; (void)out_size; (void)ws_size;
  const float* x      = (const float*)d_in[0];
  const int*   mask   = (const int*)d_in[1];
  const float* W      = (const float*)d_in[2];
  const float* U      = (const float*)d_in[3];
  const float* bias   = (const float*)d_in[4];
  const float* gammas = (const float*)d_in[5];
  const float* betas  = (const float*)d_in[6];
  float* out = (float*)d_out;

  char* ws = (char*)d_ws;
  size_t off = 0;
  auto alloc = [&](size_t bytes) -> void* {
    void* p = ws + off;
    off += (bytes + 255) & ~(size_t)255;
    return p;
  };
  float*  h_seq = (float*) alloc((size_t)TT * BB * DD * 4);
  ushort* lnXW  = (ushort*)alloc((size_t)TT * BB * NPAD * 2);
  ushort* vbuf  = (ushort*)alloc((size_t)TT * BB * NPAD * 2);
  float*  fkbuf = (float*) alloc((size_t)TT * BB * 4);
  float*  hvbuf = (float*) alloc((size_t)TT * BB * 4);
  ushort* Wpk   = (ushort*)alloc((size_t)128 * NT * 16 * 8 * 2);
  ushort* Upk   = (ushort*)alloc((size_t)128 * NT * 16 * 8 * 2);
  uint*   Upk4  = (uint*)  alloc((size_t)64 * 512 * 4 * 4);
  float*  ucol  = (float*) alloc(512 * 4);

  int npk = 128 * NT * 16 * 8;
  prepack_B<<<dim3((npk + 255) / 256), dim3(256), 0, stream>>>(W, Wpk);
  prepack_B<<<dim3((npk + 255) / 256), dim3(256), 0, stream>>>(U, Upk);
  prepack_Uhi_pk<<<dim3((64 * 512 * 4 + 255) / 256), dim3(256), 0, stream>>>(U, Upk4, ucol);

  const float* g0 = gammas,      *g1 = gammas + NC;
  const float* be0 = betas,      *be1 = betas + NC;

  // layer 0: lnXW = LN(x @ W_lo)+b ; vbuf = x @ U_lo (raw)
  gemm_ln<<<dim3(256), dim3(1024), 0, stream>>>(x, 0, 16, Wpk, lnXW, 1, g0, be0, bias);
  gemm_ln<<<dim3(256), dim3(1024), 0, stream>>>(x, 0, 16, Upk, vbuf, 0, g0, be0, bias);
  rnn_layer<<<dim3(BB), dim3(512), 0, stream>>>(0, x, h_seq, lnXW, vbuf, fkbuf, hvbuf,
                                                Upk4, ucol, mask, g1, be1, bias, out);
  for (int d = 1; d < 4; d++){
    gemm_ln<<<dim3(256), dim3(1024), 0, stream>>>(h_seq, 1, 32, Wpk, lnXW, 1, g0, be0, bias);
    rnn_layer<<<dim3(BB), dim3(512), 0, stream>>>(d, x, h_seq, lnXW, vbuf, fkbuf, hvbuf,
                                                  Upk4, ucol, mask, g1, be1, bias, out);
  }
}